// Round 12
// baseline (842.420 us; speedup 1.0000x reference)
//
#include <hip/hip_runtime.h>
#include <math.h>

#define GS    512   // nodes per group
#define GSH   9
#define NGMAX 128   // max groups per branch (G1=98 for N=50000)
#define FCAP  48    // LDS FIFO capacity per group per round
#define SCAP  10240 // group region capacity

// ---------------- pass 1: bin edges into 512-node groups ----------------

__global__ __launch_bounds__(1024) void bin_kernel(
    const int* __restrict__ s1, const int* __restrict__ d1,
    const int* __restrict__ s2, const int* __restrict__ d2,
    int* __restrict__ gcur, int* __restrict__ pairs, int E, int G1) {
  __shared__ int fifo[NGMAX][FCAP];
  __shared__ int fcnt[NGMAX];
  __shared__ int fbase[NGMAX];
  __shared__ int fpre[NGMAX + 1];
  const int* src = blockIdx.y ? s2 : s1;
  const int* dst = blockIdx.y ? d2 : d1;
  int gboff = blockIdx.y * G1;
  int tid = threadIdx.x;
  if (tid < NGMAX) fcnt[tid] = 0;
  __syncthreads();
  int e0 = blockIdx.x * 4096;
  for (int r = 0; r < 4; ++r) {
    int e = e0 + r * 1024 + tid;
    if (e < E) {
      int s = src[e], d = dst[e];
      int g = d >> GSH;
      int pk = s | ((d & (GS - 1)) << 17);
      int pos = atomicAdd(&fcnt[g], 1);
      if (pos < FCAP) fifo[g][pos] = pk;
      else {
        int gp = atomicAdd(&gcur[gboff + g], 1);
        pairs[(size_t)(gboff + g) * SCAP + gp] = pk;
      }
    }
    __syncthreads();
    if (tid < G1) {
      int c = fcnt[tid];
      if (c > FCAP) c = FCAP;
      fcnt[tid] = c;
      fbase[tid] = (c > 0) ? atomicAdd(&gcur[gboff + tid], c) : 0;
    }
    __syncthreads();
    if (tid == 0) {
      int acc = 0;
      for (int i = 0; i < G1; ++i) { fpre[i] = acc; acc += fcnt[i]; }
      fpre[G1] = acc;
    }
    __syncthreads();
    int T = fpre[G1];
    for (int t = tid; t < T; t += 1024) {
      int lo = 0, hi = G1;
      while (hi - lo > 1) { int mid = (lo + hi) >> 1; if (fpre[mid] <= t) lo = mid; else hi = mid; }
      int idx = t - fpre[lo];
      pairs[(size_t)(gboff + lo) * SCAP + fbase[lo] + idx] = fifo[lo][idx];
    }
    __syncthreads();
    if (tid < NGMAX) fcnt[tid] = 0;
    __syncthreads();
  }
}

// ---------------- pass 2: per-group node CSR, in-place ----------------

__global__ __launch_bounds__(1024) void refine_kernel(
    const int* __restrict__ gcur, int* __restrict__ pairs,
    int* __restrict__ offs, int* __restrict__ counts, int N, int G1) {
  __shared__ int stg[SCAP];
  __shared__ int hist[GS];
  __shared__ int excl[GS];
  __shared__ int wtot[8];
  int gl = blockIdx.x, br = blockIdx.y;
  int g = br * G1 + gl;
  size_t rbase = (size_t)g * SCAP;
  int rcnt = gcur[g];
  if (rcnt > SCAP) rcnt = SCAP;
  int tid = threadIdx.x;
  if (tid < GS) hist[tid] = 0;
  __syncthreads();
  for (int i = tid; i < rcnt; i += 1024) {
    int pk = pairs[rbase + i];
    stg[i] = pk;
    atomicAdd(&hist[pk >> 17], 1);
  }
  __syncthreads();
  if (tid < GS) {
    int lane = tid & 63, wv = tid >> 6;
    int v = hist[tid];
    int inc = v;
    #pragma unroll
    for (int off = 1; off < 64; off <<= 1) {
      int t = __shfl_up(inc, off);
      if (lane >= off) inc += t;
    }
    excl[tid] = inc - v;
    if (lane == 63) wtot[wv] = inc;
  }
  __syncthreads();
  if (tid == 0) {
    int a = 0;
    #pragma unroll
    for (int w = 0; w < 8; ++w) { int t = wtot[w]; wtot[w] = a; a += t; }
  }
  __syncthreads();
  if (tid < GS) excl[tid] += wtot[tid >> 6];
  __syncthreads();
  int node0 = gl * GS;
  int nloc = N - node0; if (nloc > GS) nloc = GS;
  for (int j = tid; j < nloc; j += 1024) {
    offs[br * N + node0 + j] = (int)rbase + excl[j];
    counts[br * N + node0 + j] = hist[j];
  }
  __syncthreads();
  for (int i = tid; i < rcnt; i += 1024) {
    int pk = stg[i];
    int pos = atomicAdd(&excl[pk >> 17], 1);
    pairs[rbase + pos] = pk & 0x1FFFF;
  }
}

// ---------------- GEMM both branches, W register double-buffer prefetch ----------------
// Y[br][nrows,COUT] = X[br] @ W[br] + b[br]. W rows are wave-uniform -> L1 hits;
// prefetch next k-chunk's 4 W rows into regs while FMA-ing current chunk.

template <int COUT>
__global__ __launch_bounds__(256, 4) void gemm2_kernel(
    const float* __restrict__ X0, const float* __restrict__ X1,
    const float* __restrict__ W0, const float* __restrict__ W1,
    const float* __restrict__ bias0, const float* __restrict__ bias1,
    float* __restrict__ Y0, float* __restrict__ Y1, int nrows) {
  constexpr int CG = COUT / 4;
  constexpr int RG = 256 / CG;
  constexpr int BM = 64;
  constexpr int RPT = BM / RG;
  const float* X = blockIdx.y ? X1 : X0;
  const float* W = blockIdx.y ? W1 : W0;
  const float* bias = blockIdx.y ? bias1 : bias0;
  float* Y = blockIdx.y ? Y1 : Y0;
  __shared__ float xs[BM][132];
  int tid = threadIdx.x;
  int block_row = blockIdx.x * BM;
  for (int i = tid; i < BM * 32; i += 256) {
    int r = i >> 5, c4 = i & 31;
    int gr = block_row + r;
    float4 v = make_float4(0.f, 0.f, 0.f, 0.f);
    if (gr < nrows) v = reinterpret_cast<const float4*>(X + (size_t)gr * 128)[c4];
    *reinterpret_cast<float4*>(&xs[r][c4 * 4]) = v;
  }
  __syncthreads();
  int c0 = (tid % CG) * 4;
  int r0 = (tid / CG) * RPT;
  const float* Wp = W + c0;
  float acc[RPT][4] = {};
  float4 wb0 = *reinterpret_cast<const float4*>(Wp + 0 * COUT);
  float4 wb1 = *reinterpret_cast<const float4*>(Wp + 1 * COUT);
  float4 wb2 = *reinterpret_cast<const float4*>(Wp + 2 * COUT);
  float4 wb3 = *reinterpret_cast<const float4*>(Wp + 3 * COUT);
  #pragma unroll 4
  for (int k = 0; k < 128; k += 4) {
    float4 w0 = wb0, w1 = wb1, w2 = wb2, w3 = wb3;
    if (k + 4 < 128) {
      wb0 = *reinterpret_cast<const float4*>(Wp + (k + 4) * COUT);
      wb1 = *reinterpret_cast<const float4*>(Wp + (k + 5) * COUT);
      wb2 = *reinterpret_cast<const float4*>(Wp + (k + 6) * COUT);
      wb3 = *reinterpret_cast<const float4*>(Wp + (k + 7) * COUT);
    }
    #pragma unroll
    for (int i = 0; i < RPT; ++i) {
      float4 x = *reinterpret_cast<const float4*>(&xs[r0 + i][k]);
      acc[i][0] = fmaf(x.x, w0.x, acc[i][0]);
      acc[i][1] = fmaf(x.x, w0.y, acc[i][1]);
      acc[i][2] = fmaf(x.x, w0.z, acc[i][2]);
      acc[i][3] = fmaf(x.x, w0.w, acc[i][3]);
      acc[i][0] = fmaf(x.y, w1.x, acc[i][0]);
      acc[i][1] = fmaf(x.y, w1.y, acc[i][1]);
      acc[i][2] = fmaf(x.y, w1.z, acc[i][2]);
      acc[i][3] = fmaf(x.y, w1.w, acc[i][3]);
      acc[i][0] = fmaf(x.z, w2.x, acc[i][0]);
      acc[i][1] = fmaf(x.z, w2.y, acc[i][1]);
      acc[i][2] = fmaf(x.z, w2.z, acc[i][2]);
      acc[i][3] = fmaf(x.z, w2.w, acc[i][3]);
      acc[i][0] = fmaf(x.w, w3.x, acc[i][0]);
      acc[i][1] = fmaf(x.w, w3.y, acc[i][1]);
      acc[i][2] = fmaf(x.w, w3.z, acc[i][2]);
      acc[i][3] = fmaf(x.w, w3.w, acc[i][3]);
    }
  }
  float4 bv = *reinterpret_cast<const float4*>(&bias[c0]);
  #pragma unroll
  for (int i = 0; i < RPT; ++i) {
    int gr = block_row + r0 + i;
    if (gr < nrows) {
      float4 o;
      o.x = acc[i][0] + bv.x; o.y = acc[i][1] + bv.y;
      o.z = acc[i][2] + bv.z; o.w = acc[i][3] + bv.w;
      *reinterpret_cast<float4*>(&Y[(size_t)gr * COUT + c0]) = o;
    }
  }
}

// ---------------- agg C=128, column-split (blockIdx.y = col half) ----------------

__global__ __launch_bounds__(256) void agg128_kernel(
    const float* __restrict__ h, const int* __restrict__ offs,
    const int* __restrict__ counts, const int* __restrict__ csr_src,
    const float* __restrict__ gamma, const float* __restrict__ beta,
    float* __restrict__ out, int n) {
  int node = blockIdx.x * 4 + (threadIdx.x >> 6);
  if (node >= n) return;
  node = __builtin_amdgcn_readfirstlane(node);
  int ch = blockIdx.y;
  int lane = threadIdx.x & 63;
  int half = lane >> 5;
  int l5 = lane & 31;
  const float* hh = h + ch * 64;
  int beg = offs[node], cnt = counts[node];
  const int* lp = csr_src + beg;
  float a0 = 0.f, a1 = 0.f;
  for (int base = 0; base < cnt; base += 64) {
    int rem = cnt - base;
    int m = rem < 64 ? rem : 64;
    int idx = lp[base + (lane < m ? lane : m - 1)];
    int mfull = m & ~15;
    int j = 0;
    for (; j < mfull; j += 16) {
      float2 v[8];
      #pragma unroll
      for (int u = 0; u < 8; ++u) {
        int s = __shfl(idx, j + 2 * u + half);
        v[u] = *reinterpret_cast<const float2*>(hh + (size_t)s * 128 + l5 * 2);
      }
      #pragma unroll
      for (int u = 0; u < 8; ++u) { a0 += v[u].x; a1 += v[u].y; }
    }
    if (j < m) {
      float2 v[8];
      #pragma unroll
      for (int u = 0; u < 8; ++u) {
        int ed = j + 2 * u + half;
        int s = __shfl(idx, ed < m ? ed : m - 1);
        v[u] = *reinterpret_cast<const float2*>(hh + (size_t)s * 128 + l5 * 2);
      }
      #pragma unroll
      for (int u = 0; u < 8; ++u) {
        bool ok = (j + 2 * u + half) < m;
        a0 += ok ? v[u].x : 0.f;
        a1 += ok ? v[u].y : 0.f;
      }
    }
  }
  a0 += __shfl_xor(a0, 32);
  a1 += __shfl_xor(a1, 32);
  const float inv = 1.0f / sqrtf(1.0f + 1.0e-3f);
  if (half == 0) {
    float2 g = reinterpret_cast<const float2*>(gamma + ch * 64)[l5];
    float2 b = reinterpret_cast<const float2*>(beta + ch * 64)[l5];
    float2 o;
    o.x = fmaxf(fmaf(a0, g.x * inv, b.x), 0.f);
    o.y = fmaxf(fmaf(a1, g.y * inv, b.y), 0.f);
    *reinterpret_cast<float2*>(out + (size_t)node * 128 + ch * 64 + l5 * 2) = o;
  }
}

// ---------------- agg C=64 ----------------

__global__ __launch_bounds__(256) void agg64_kernel(
    const float* __restrict__ h, const int* __restrict__ offs,
    const int* __restrict__ counts, const int* __restrict__ csr_src,
    const float* __restrict__ gamma, const float* __restrict__ beta,
    float* __restrict__ out, int n) {
  int node = blockIdx.x * 4 + (threadIdx.x >> 6);
  if (node >= n) return;
  node = __builtin_amdgcn_readfirstlane(node);
  int lane = threadIdx.x & 63;
  int half = lane >> 5;
  int l5 = lane & 31;
  int beg = offs[node], cnt = counts[node];
  const int* lp = csr_src + beg;
  float a0 = 0.f, a1 = 0.f;
  for (int base = 0; base < cnt; base += 64) {
    int rem = cnt - base;
    int m = rem < 64 ? rem : 64;
    int idx = lp[base + (lane < m ? lane : m - 1)];
    int mfull = m & ~15;
    int j = 0;
    for (; j < mfull; j += 16) {
      float2 v[8];
      #pragma unroll
      for (int u = 0; u < 8; ++u) {
        int s = __shfl(idx, j + 2 * u + half);
        v[u] = *reinterpret_cast<const float2*>(h + (size_t)s * 64 + l5 * 2);
      }
      #pragma unroll
      for (int u = 0; u < 8; ++u) { a0 += v[u].x; a1 += v[u].y; }
    }
    if (j < m) {
      float2 v[8];
      #pragma unroll
      for (int u = 0; u < 8; ++u) {
        int ed = j + 2 * u + half;
        int s = __shfl(idx, ed < m ? ed : m - 1);
        v[u] = *reinterpret_cast<const float2*>(h + (size_t)s * 64 + l5 * 2);
      }
      #pragma unroll
      for (int u = 0; u < 8; ++u) {
        bool ok = (j + 2 * u + half) < m;
        a0 += ok ? v[u].x : 0.f;
        a1 += ok ? v[u].y : 0.f;
      }
    }
  }
  a0 += __shfl_xor(a0, 32);
  a1 += __shfl_xor(a1, 32);
  const float inv = 1.0f / sqrtf(1.0f + 1.0e-3f);
  if (half == 0) {
    float2 g = reinterpret_cast<const float2*>(gamma)[l5];
    float2 b = reinterpret_cast<const float2*>(beta)[l5];
    float2 o;
    o.x = fmaxf(fmaf(a0, g.x * inv, b.x), 0.f);
    o.y = fmaxf(fmaf(a1, g.y * inv, b.y), 0.f);
    *reinterpret_cast<float2*>(out + (size_t)node * 64 + l5 * 2) = o;
  }
}

// ---------------- Segment mean pool, both branches ----------------

__global__ __launch_bounds__(1024) void pool2_kernel(
    const float* __restrict__ h0, const float* __restrict__ h1,
    const int* __restrict__ seg0, const int* __restrict__ seg1,
    float* __restrict__ p, int n) {
  const float* h = blockIdx.y ? h1 : h0;
  const int* seg = blockIdx.y ? seg1 : seg0;
  float* pb = p + blockIdx.y * 64 * 64;
  int g = blockIdx.x;
  int lo, hi;
  { int l = 0, r = n; while (l < r) { int m = (l + r) >> 1; if (seg[m] < g) l = m + 1; else r = m; } lo = l; }
  { int l = 0, r = n; while (l < r) { int m = (l + r) >> 1; if (seg[m] < g + 1) l = m + 1; else r = m; } hi = l; }
  int c = threadIdx.x & 63;
  int sub = threadIdx.x >> 6;
  float acc = 0.f;
  for (int i = lo + sub; i < hi; i += 16) acc += h[(size_t)i * 64 + c];
  __shared__ float red[16][64];
  red[sub][c] = acc;
  __syncthreads();
  if (sub == 0) {
    float s = 0.f;
    #pragma unroll
    for (int k = 0; k < 16; ++k) s += red[k][c];
    float cnt = (float)(hi - lo);
    pb[g * 64 + c] = s / fmaxf(cnt, 1.0f);
  }
}

// ---------------- Head ----------------

__global__ __launch_bounds__(512) void head_kernel(const float* __restrict__ p,
                                                   const float* __restrict__ Wd,
                                                   const float* __restrict__ bd,
                                                   const float* __restrict__ Wo,
                                                   const float* __restrict__ bo,
                                                   float* __restrict__ out) {
  __shared__ float cur[64][128];
  __shared__ float nxt[64][128];
  int tid = threadIdx.x;
  const float* p1 = p;
  const float* p2 = p + 64 * 64;
  for (int i = tid; i < 64 * 128; i += 512) {
    int r = i >> 7, c = i & 127;
    cur[r][c] = (c < 64) ? p1[r * 64 + c] : p2[r * 64 + (c - 64)];
  }
  __syncthreads();
  int c0 = (tid & 31) * 4;
  int r0 = (tid >> 5) * 4;
  for (int layer = 0; layer < 2; ++layer) {
    float acc[4][4] = {};
    #pragma unroll 4
    for (int k = 0; k < 128; ++k) {
      float4 w = *reinterpret_cast<const float4*>(&Wd[k * 128 + c0]);
      #pragma unroll
      for (int i = 0; i < 4; ++i) {
        float x = cur[r0 + i][k];
        acc[i][0] = fmaf(x, w.x, acc[i][0]);
        acc[i][1] = fmaf(x, w.y, acc[i][1]);
        acc[i][2] = fmaf(x, w.z, acc[i][2]);
        acc[i][3] = fmaf(x, w.w, acc[i][3]);
      }
    }
    float4 bv = *reinterpret_cast<const float4*>(&bd[c0]);
    __syncthreads();
    #pragma unroll
    for (int i = 0; i < 4; ++i) {
      float4 o;
      o.x = fmaxf(acc[i][0] + bv.x, 0.f);
      o.y = fmaxf(acc[i][1] + bv.y, 0.f);
      o.z = fmaxf(acc[i][2] + bv.z, 0.f);
      o.w = fmaxf(acc[i][3] + bv.w, 0.f);
      *reinterpret_cast<float4*>(&nxt[r0 + i][c0]) = o;
    }
    __syncthreads();
    for (int i = tid; i < 64 * 128; i += 512) (&cur[0][0])[i] = (&nxt[0][0])[i];
    __syncthreads();
  }
  int wv = tid >> 6, lane = tid & 63;
  for (int r = wv; r < 64; r += 8) {
    float v = cur[r][lane] * Wo[lane] + cur[r][64 + lane] * Wo[64 + lane];
    #pragma unroll
    for (int off = 32; off; off >>= 1) v += __shfl_down(v, off);
    if (lane == 0) out[r] = 1.0f / (1.0f + expf(-(v + bo[0])));
  }
}

// ---------------- launch ----------------

extern "C" void kernel_launch(void* const* d_in, const int* in_sizes, int n_in,
                              void* d_out, int out_size, void* d_ws, size_t ws_size,
                              hipStream_t stream) {
  const float* x1  = (const float*)d_in[0];
  const float* x2  = (const float*)d_in[1];
  const int* e1    = (const int*)d_in[2];
  const int* e2    = (const int*)d_in[3];
  const int* seg1  = (const int*)d_in[4];
  const int* seg2  = (const int*)d_in[5];
  const float* W1a = (const float*)d_in[6];  const float* b1a = (const float*)d_in[7];
  const float* g1a = (const float*)d_in[8];  const float* be1a = (const float*)d_in[9];
  const float* W1b = (const float*)d_in[10]; const float* b1b = (const float*)d_in[11];
  const float* g1b = (const float*)d_in[12]; const float* be1b = (const float*)d_in[13];
  const float* W2a = (const float*)d_in[14]; const float* b2a = (const float*)d_in[15];
  const float* g2a = (const float*)d_in[16]; const float* be2a = (const float*)d_in[17];
  const float* W2b = (const float*)d_in[18]; const float* b2b = (const float*)d_in[19];
  const float* g2b = (const float*)d_in[20]; const float* be2b = (const float*)d_in[21];
  const float* Wd  = (const float*)d_in[22]; const float* bd  = (const float*)d_in[23];
  const float* Wo  = (const float*)d_in[24]; const float* bo  = (const float*)d_in[25];
  float* out = (float*)d_out;

  const int N = in_sizes[0] / 128;
  const int E = in_sizes[2] / 2;
  const int G1 = (N + GS - 1) >> GSH;
  const int G  = 2 * G1;

  char* ws = (char*)d_ws;
  size_t off = 0;
  auto alloc = [&](size_t bytes) -> void* {
    void* ptr = ws + off;
    off += (bytes + 255) & ~(size_t)255;
    return ptr;
  };
  float* h0   = (float*)alloc((size_t)N * 128 * sizeof(float));
  float* h1   = (float*)alloc((size_t)N * 128 * sizeof(float));
  float* ag0  = (float*)alloc((size_t)N * 128 * sizeof(float));
  float* ag1  = (float*)alloc((size_t)N * 128 * sizeof(float));
  int* pairs  = (int*)alloc((size_t)G * SCAP * sizeof(int));
  int* offs   = (int*)alloc((size_t)(2 * N) * sizeof(int));
  int* counts = (int*)alloc((size_t)(2 * N) * sizeof(int));
  int* gcur   = (int*)alloc((size_t)(G + 8) * sizeof(int));
  float* pbuf = (float*)alloc(2 * 64 * 64 * sizeof(float));
  (void)ws_size; (void)n_in; (void)out_size;

  // ---- CSR build ----
  hipMemsetAsync(gcur, 0, (size_t)(G + 8) * sizeof(int), stream);
  {
    dim3 gb((E + 4095) / 4096, 2);
    bin_kernel<<<gb, 1024, 0, stream>>>(e1, e1 + E, e2, e2 + E, gcur, pairs, E, G1);
    dim3 gr(G1, 2);
    refine_kernel<<<gr, 1024, 0, stream>>>(gcur, pairs, offs, counts, N, G1);
  }

  const int* offs0 = offs;       const int* cnts0 = counts;
  const int* offs1 = offs + N;   const int* cnts1 = counts + N;

  // layer 1
  {
    dim3 gg((N + 63) / 64, 2);
    gemm2_kernel<128><<<gg, 256, 0, stream>>>(x1, x2, W1a, W2a, b1a, b2a, h0, h1, N);
  }
  {
    dim3 ga((N + 3) / 4, 2);
    agg128_kernel<<<ga, 256, 0, stream>>>(h0, offs0, cnts0, pairs, g1a, be1a, ag0, N);
    agg128_kernel<<<ga, 256, 0, stream>>>(h1, offs1, cnts1, pairs, g2a, be2a, ag1, N);
  }
  // layer 2
  {
    dim3 gg((N + 63) / 64, 2);
    gemm2_kernel<64><<<gg, 256, 0, stream>>>(ag0, ag1, W1b, W2b, b1b, b2b, h0, h1, N);
  }
  agg64_kernel<<<(N + 3) / 4, 256, 0, stream>>>(h0, offs0, cnts0, pairs, g1b, be1b, ag0, N);
  agg64_kernel<<<(N + 3) / 4, 256, 0, stream>>>(h1, offs1, cnts1, pairs, g2b, be2b, ag1, N);
  // pool + head
  {
    dim3 gp(64, 2);
    pool2_kernel<<<gp, 1024, 0, stream>>>(ag0, ag1, seg1, seg2, pbuf, N);
  }
  head_kernel<<<1, 512, 0, stream>>>(pbuf, Wd, bd, Wo, bo, out);
}

// Round 13
// 366.868 us; speedup vs baseline: 2.2962x; 2.2962x over previous
//
#include <hip/hip_runtime.h>
#include <math.h>

#define GS    512   // nodes per group
#define GSH   9
#define NGMAX 128   // max groups per branch (G1=98 for N=50000)
#define FCAP  48    // LDS FIFO capacity per group per round
#define SCAP  10240 // group region capacity

// ---------------- pass 1: bin edges into 512-node groups ----------------

__global__ __launch_bounds__(1024) void bin_kernel(
    const int* __restrict__ s1, const int* __restrict__ d1,
    const int* __restrict__ s2, const int* __restrict__ d2,
    int* __restrict__ gcur, int* __restrict__ pairs, int E, int G1) {
  __shared__ int fifo[NGMAX][FCAP];
  __shared__ int fcnt[NGMAX];
  __shared__ int fbase[NGMAX];
  __shared__ int fpre[NGMAX + 1];
  const int* src = blockIdx.y ? s2 : s1;
  const int* dst = blockIdx.y ? d2 : d1;
  int gboff = blockIdx.y * G1;
  int tid = threadIdx.x;
  if (tid < NGMAX) fcnt[tid] = 0;
  __syncthreads();
  int e0 = blockIdx.x * 4096;
  for (int r = 0; r < 4; ++r) {
    int e = e0 + r * 1024 + tid;
    if (e < E) {
      int s = src[e], d = dst[e];
      int g = d >> GSH;
      int pk = s | ((d & (GS - 1)) << 17);
      int pos = atomicAdd(&fcnt[g], 1);
      if (pos < FCAP) fifo[g][pos] = pk;
      else {
        int gp = atomicAdd(&gcur[gboff + g], 1);
        pairs[(size_t)(gboff + g) * SCAP + gp] = pk;
      }
    }
    __syncthreads();
    if (tid < G1) {
      int c = fcnt[tid];
      if (c > FCAP) c = FCAP;
      fcnt[tid] = c;
      fbase[tid] = (c > 0) ? atomicAdd(&gcur[gboff + tid], c) : 0;
    }
    __syncthreads();
    if (tid == 0) {
      int acc = 0;
      for (int i = 0; i < G1; ++i) { fpre[i] = acc; acc += fcnt[i]; }
      fpre[G1] = acc;
    }
    __syncthreads();
    int T = fpre[G1];
    for (int t = tid; t < T; t += 1024) {
      int lo = 0, hi = G1;
      while (hi - lo > 1) { int mid = (lo + hi) >> 1; if (fpre[mid] <= t) lo = mid; else hi = mid; }
      int idx = t - fpre[lo];
      pairs[(size_t)(gboff + lo) * SCAP + fbase[lo] + idx] = fifo[lo][idx];
    }
    __syncthreads();
    if (tid < NGMAX) fcnt[tid] = 0;
    __syncthreads();
  }
}

// ---------------- pass 2: per-group node CSR, in-place ----------------

__global__ __launch_bounds__(1024) void refine_kernel(
    const int* __restrict__ gcur, int* __restrict__ pairs,
    int* __restrict__ offs, int* __restrict__ counts, int N, int G1) {
  __shared__ int stg[SCAP];
  __shared__ int hist[GS];
  __shared__ int excl[GS];
  __shared__ int wtot[8];
  int gl = blockIdx.x, br = blockIdx.y;
  int g = br * G1 + gl;
  size_t rbase = (size_t)g * SCAP;
  int rcnt = gcur[g];
  if (rcnt > SCAP) rcnt = SCAP;
  int tid = threadIdx.x;
  if (tid < GS) hist[tid] = 0;
  __syncthreads();
  for (int i = tid; i < rcnt; i += 1024) {
    int pk = pairs[rbase + i];
    stg[i] = pk;
    atomicAdd(&hist[pk >> 17], 1);
  }
  __syncthreads();
  if (tid < GS) {
    int lane = tid & 63, wv = tid >> 6;
    int v = hist[tid];
    int inc = v;
    #pragma unroll
    for (int off = 1; off < 64; off <<= 1) {
      int t = __shfl_up(inc, off);
      if (lane >= off) inc += t;
    }
    excl[tid] = inc - v;
    if (lane == 63) wtot[wv] = inc;
  }
  __syncthreads();
  if (tid == 0) {
    int a = 0;
    #pragma unroll
    for (int w = 0; w < 8; ++w) { int t = wtot[w]; wtot[w] = a; a += t; }
  }
  __syncthreads();
  if (tid < GS) excl[tid] += wtot[tid >> 6];
  __syncthreads();
  int node0 = gl * GS;
  int nloc = N - node0; if (nloc > GS) nloc = GS;
  for (int j = tid; j < nloc; j += 1024) {
    offs[br * N + node0 + j] = (int)rbase + excl[j];
    counts[br * N + node0 + j] = hist[j];
  }
  __syncthreads();
  for (int i = tid; i < rcnt; i += 1024) {
    int pk = stg[i];
    int pos = atomicAdd(&excl[pk >> 17], 1);
    pairs[rbase + pos] = pk & 0x1FFFF;
  }
}

// ---------------- GEMM both branches: BM=32, high occupancy ----------------
// Y[br][nrows,COUT] = X[br] @ W[br] + b[br]. W rows wave-uniform -> L1 hits.
// LDS 16.9KB -> 8 blocks/CU (wave-slot-bound); acc 16 regs, no spill.

template <int COUT>
__global__ __launch_bounds__(256, 2) void gemm2_kernel(
    const float* __restrict__ X0, const float* __restrict__ X1,
    const float* __restrict__ W0, const float* __restrict__ W1,
    const float* __restrict__ bias0, const float* __restrict__ bias1,
    float* __restrict__ Y0, float* __restrict__ Y1, int nrows) {
  constexpr int CG = COUT / 4;     // 32 / 16
  constexpr int RG = 256 / CG;     // 8 / 16
  constexpr int BM = 32;
  constexpr int RPT = BM / RG;     // 4 / 2
  const float* X = blockIdx.y ? X1 : X0;
  const float* W = blockIdx.y ? W1 : W0;
  const float* bias = blockIdx.y ? bias1 : bias0;
  float* Y = blockIdx.y ? Y1 : Y0;
  __shared__ float xs[BM][132];
  int tid = threadIdx.x;
  int block_row = blockIdx.x * BM;
  for (int i = tid; i < BM * 32; i += 256) {
    int r = i >> 5, c4 = i & 31;
    int gr = block_row + r;
    float4 v = make_float4(0.f, 0.f, 0.f, 0.f);
    if (gr < nrows) v = reinterpret_cast<const float4*>(X + (size_t)gr * 128)[c4];
    *reinterpret_cast<float4*>(&xs[r][c4 * 4]) = v;
  }
  __syncthreads();
  int c0 = (tid % CG) * 4;
  int r0 = (tid / CG) * RPT;
  float acc[RPT][4] = {};
  #pragma unroll 2
  for (int k = 0; k < 128; k += 4) {
    float4 w0 = *reinterpret_cast<const float4*>(&W[(k + 0) * COUT + c0]);
    float4 w1 = *reinterpret_cast<const float4*>(&W[(k + 1) * COUT + c0]);
    float4 w2 = *reinterpret_cast<const float4*>(&W[(k + 2) * COUT + c0]);
    float4 w3 = *reinterpret_cast<const float4*>(&W[(k + 3) * COUT + c0]);
    #pragma unroll
    for (int i = 0; i < RPT; ++i) {
      float4 x = *reinterpret_cast<const float4*>(&xs[r0 + i][k]);
      acc[i][0] = fmaf(x.x, w0.x, acc[i][0]);
      acc[i][1] = fmaf(x.x, w0.y, acc[i][1]);
      acc[i][2] = fmaf(x.x, w0.z, acc[i][2]);
      acc[i][3] = fmaf(x.x, w0.w, acc[i][3]);
      acc[i][0] = fmaf(x.y, w1.x, acc[i][0]);
      acc[i][1] = fmaf(x.y, w1.y, acc[i][1]);
      acc[i][2] = fmaf(x.y, w1.z, acc[i][2]);
      acc[i][3] = fmaf(x.y, w1.w, acc[i][3]);
      acc[i][0] = fmaf(x.z, w2.x, acc[i][0]);
      acc[i][1] = fmaf(x.z, w2.y, acc[i][1]);
      acc[i][2] = fmaf(x.z, w2.z, acc[i][2]);
      acc[i][3] = fmaf(x.z, w2.w, acc[i][3]);
      acc[i][0] = fmaf(x.w, w3.x, acc[i][0]);
      acc[i][1] = fmaf(x.w, w3.y, acc[i][1]);
      acc[i][2] = fmaf(x.w, w3.z, acc[i][2]);
      acc[i][3] = fmaf(x.w, w3.w, acc[i][3]);
    }
  }
  float4 bv = *reinterpret_cast<const float4*>(&bias[c0]);
  #pragma unroll
  for (int i = 0; i < RPT; ++i) {
    int gr = block_row + r0 + i;
    if (gr < nrows) {
      float4 o;
      o.x = acc[i][0] + bv.x; o.y = acc[i][1] + bv.y;
      o.z = acc[i][2] + bv.z; o.w = acc[i][3] + bv.w;
      *reinterpret_cast<float4*>(&Y[(size_t)gr * COUT + c0]) = o;
    }
  }
}

// ---------------- agg C=128, column-split (blockIdx.y = col half) ----------------

__global__ __launch_bounds__(256) void agg128_kernel(
    const float* __restrict__ h, const int* __restrict__ offs,
    const int* __restrict__ counts, const int* __restrict__ csr_src,
    const float* __restrict__ gamma, const float* __restrict__ beta,
    float* __restrict__ out, int n) {
  int node = blockIdx.x * 4 + (threadIdx.x >> 6);
  if (node >= n) return;
  node = __builtin_amdgcn_readfirstlane(node);
  int ch = blockIdx.y;
  int lane = threadIdx.x & 63;
  int half = lane >> 5;
  int l5 = lane & 31;
  const float* hh = h + ch * 64;
  int beg = offs[node], cnt = counts[node];
  const int* lp = csr_src + beg;
  float a0 = 0.f, a1 = 0.f;
  for (int base = 0; base < cnt; base += 64) {
    int rem = cnt - base;
    int m = rem < 64 ? rem : 64;
    int idx = lp[base + (lane < m ? lane : m - 1)];
    int mfull = m & ~15;
    int j = 0;
    for (; j < mfull; j += 16) {
      float2 v[8];
      #pragma unroll
      for (int u = 0; u < 8; ++u) {
        int s = __shfl(idx, j + 2 * u + half);
        v[u] = *reinterpret_cast<const float2*>(hh + (size_t)s * 128 + l5 * 2);
      }
      #pragma unroll
      for (int u = 0; u < 8; ++u) { a0 += v[u].x; a1 += v[u].y; }
    }
    if (j < m) {
      float2 v[8];
      #pragma unroll
      for (int u = 0; u < 8; ++u) {
        int ed = j + 2 * u + half;
        int s = __shfl(idx, ed < m ? ed : m - 1);
        v[u] = *reinterpret_cast<const float2*>(hh + (size_t)s * 128 + l5 * 2);
      }
      #pragma unroll
      for (int u = 0; u < 8; ++u) {
        bool ok = (j + 2 * u + half) < m;
        a0 += ok ? v[u].x : 0.f;
        a1 += ok ? v[u].y : 0.f;
      }
    }
  }
  a0 += __shfl_xor(a0, 32);
  a1 += __shfl_xor(a1, 32);
  const float inv = 1.0f / sqrtf(1.0f + 1.0e-3f);
  if (half == 0) {
    float2 g = reinterpret_cast<const float2*>(gamma + ch * 64)[l5];
    float2 b = reinterpret_cast<const float2*>(beta + ch * 64)[l5];
    float2 o;
    o.x = fmaxf(fmaf(a0, g.x * inv, b.x), 0.f);
    o.y = fmaxf(fmaf(a1, g.y * inv, b.y), 0.f);
    *reinterpret_cast<float2*>(out + (size_t)node * 128 + ch * 64 + l5 * 2) = o;
  }
}

// ---------------- agg C=64 ----------------

__global__ __launch_bounds__(256) void agg64_kernel(
    const float* __restrict__ h, const int* __restrict__ offs,
    const int* __restrict__ counts, const int* __restrict__ csr_src,
    const float* __restrict__ gamma, const float* __restrict__ beta,
    float* __restrict__ out, int n) {
  int node = blockIdx.x * 4 + (threadIdx.x >> 6);
  if (node >= n) return;
  node = __builtin_amdgcn_readfirstlane(node);
  int lane = threadIdx.x & 63;
  int half = lane >> 5;
  int l5 = lane & 31;
  int beg = offs[node], cnt = counts[node];
  const int* lp = csr_src + beg;
  float a0 = 0.f, a1 = 0.f;
  for (int base = 0; base < cnt; base += 64) {
    int rem = cnt - base;
    int m = rem < 64 ? rem : 64;
    int idx = lp[base + (lane < m ? lane : m - 1)];
    int mfull = m & ~15;
    int j = 0;
    for (; j < mfull; j += 16) {
      float2 v[8];
      #pragma unroll
      for (int u = 0; u < 8; ++u) {
        int s = __shfl(idx, j + 2 * u + half);
        v[u] = *reinterpret_cast<const float2*>(h + (size_t)s * 64 + l5 * 2);
      }
      #pragma unroll
      for (int u = 0; u < 8; ++u) { a0 += v[u].x; a1 += v[u].y; }
    }
    if (j < m) {
      float2 v[8];
      #pragma unroll
      for (int u = 0; u < 8; ++u) {
        int ed = j + 2 * u + half;
        int s = __shfl(idx, ed < m ? ed : m - 1);
        v[u] = *reinterpret_cast<const float2*>(h + (size_t)s * 64 + l5 * 2);
      }
      #pragma unroll
      for (int u = 0; u < 8; ++u) {
        bool ok = (j + 2 * u + half) < m;
        a0 += ok ? v[u].x : 0.f;
        a1 += ok ? v[u].y : 0.f;
      }
    }
  }
  a0 += __shfl_xor(a0, 32);
  a1 += __shfl_xor(a1, 32);
  const float inv = 1.0f / sqrtf(1.0f + 1.0e-3f);
  if (half == 0) {
    float2 g = reinterpret_cast<const float2*>(gamma)[l5];
    float2 b = reinterpret_cast<const float2*>(beta)[l5];
    float2 o;
    o.x = fmaxf(fmaf(a0, g.x * inv, b.x), 0.f);
    o.y = fmaxf(fmaf(a1, g.y * inv, b.y), 0.f);
    *reinterpret_cast<float2*>(out + (size_t)node * 64 + l5 * 2) = o;
  }
}

// ---------------- Segment mean pool, both branches ----------------

__global__ __launch_bounds__(1024) void pool2_kernel(
    const float* __restrict__ h0, const float* __restrict__ h1,
    const int* __restrict__ seg0, const int* __restrict__ seg1,
    float* __restrict__ p, int n) {
  const float* h = blockIdx.y ? h1 : h0;
  const int* seg = blockIdx.y ? seg1 : seg0;
  float* pb = p + blockIdx.y * 64 * 64;
  int g = blockIdx.x;
  int lo, hi;
  { int l = 0, r = n; while (l < r) { int m = (l + r) >> 1; if (seg[m] < g) l = m + 1; else r = m; } lo = l; }
  { int l = 0, r = n; while (l < r) { int m = (l + r) >> 1; if (seg[m] < g + 1) l = m + 1; else r = m; } hi = l; }
  int c = threadIdx.x & 63;
  int sub = threadIdx.x >> 6;
  float acc = 0.f;
  for (int i = lo + sub; i < hi; i += 16) acc += h[(size_t)i * 64 + c];
  __shared__ float red[16][64];
  red[sub][c] = acc;
  __syncthreads();
  if (sub == 0) {
    float s = 0.f;
    #pragma unroll
    for (int k = 0; k < 16; ++k) s += red[k][c];
    float cnt = (float)(hi - lo);
    pb[g * 64 + c] = s / fmaxf(cnt, 1.0f);
  }
}

// ---------------- Head ----------------

__global__ __launch_bounds__(512) void head_kernel(const float* __restrict__ p,
                                                   const float* __restrict__ Wd,
                                                   const float* __restrict__ bd,
                                                   const float* __restrict__ Wo,
                                                   const float* __restrict__ bo,
                                                   float* __restrict__ out) {
  __shared__ float cur[64][128];
  __shared__ float nxt[64][128];
  int tid = threadIdx.x;
  const float* p1 = p;
  const float* p2 = p + 64 * 64;
  for (int i = tid; i < 64 * 128; i += 512) {
    int r = i >> 7, c = i & 127;
    cur[r][c] = (c < 64) ? p1[r * 64 + c] : p2[r * 64 + (c - 64)];
  }
  __syncthreads();
  int c0 = (tid & 31) * 4;
  int r0 = (tid >> 5) * 4;
  for (int layer = 0; layer < 2; ++layer) {
    float acc[4][4] = {};
    #pragma unroll 4
    for (int k = 0; k < 128; ++k) {
      float4 w = *reinterpret_cast<const float4*>(&Wd[k * 128 + c0]);
      #pragma unroll
      for (int i = 0; i < 4; ++i) {
        float x = cur[r0 + i][k];
        acc[i][0] = fmaf(x, w.x, acc[i][0]);
        acc[i][1] = fmaf(x, w.y, acc[i][1]);
        acc[i][2] = fmaf(x, w.z, acc[i][2]);
        acc[i][3] = fmaf(x, w.w, acc[i][3]);
      }
    }
    float4 bv = *reinterpret_cast<const float4*>(&bd[c0]);
    __syncthreads();
    #pragma unroll
    for (int i = 0; i < 4; ++i) {
      float4 o;
      o.x = fmaxf(acc[i][0] + bv.x, 0.f);
      o.y = fmaxf(acc[i][1] + bv.y, 0.f);
      o.z = fmaxf(acc[i][2] + bv.z, 0.f);
      o.w = fmaxf(acc[i][3] + bv.w, 0.f);
      *reinterpret_cast<float4*>(&nxt[r0 + i][c0]) = o;
    }
    __syncthreads();
    for (int i = tid; i < 64 * 128; i += 512) (&cur[0][0])[i] = (&nxt[0][0])[i];
    __syncthreads();
  }
  int wv = tid >> 6, lane = tid & 63;
  for (int r = wv; r < 64; r += 8) {
    float v = cur[r][lane] * Wo[lane] + cur[r][64 + lane] * Wo[64 + lane];
    #pragma unroll
    for (int off = 32; off; off >>= 1) v += __shfl_down(v, off);
    if (lane == 0) out[r] = 1.0f / (1.0f + expf(-(v + bo[0])));
  }
}

// ---------------- launch ----------------

extern "C" void kernel_launch(void* const* d_in, const int* in_sizes, int n_in,
                              void* d_out, int out_size, void* d_ws, size_t ws_size,
                              hipStream_t stream) {
  const float* x1  = (const float*)d_in[0];
  const float* x2  = (const float*)d_in[1];
  const int* e1    = (const int*)d_in[2];
  const int* e2    = (const int*)d_in[3];
  const int* seg1  = (const int*)d_in[4];
  const int* seg2  = (const int*)d_in[5];
  const float* W1a = (const float*)d_in[6];  const float* b1a = (const float*)d_in[7];
  const float* g1a = (const float*)d_in[8];  const float* be1a = (const float*)d_in[9];
  const float* W1b = (const float*)d_in[10]; const float* b1b = (const float*)d_in[11];
  const float* g1b = (const float*)d_in[12]; const float* be1b = (const float*)d_in[13];
  const float* W2a = (const float*)d_in[14]; const float* b2a = (const float*)d_in[15];
  const float* g2a = (const float*)d_in[16]; const float* be2a = (const float*)d_in[17];
  const float* W2b = (const float*)d_in[18]; const float* b2b = (const float*)d_in[19];
  const float* g2b = (const float*)d_in[20]; const float* be2b = (const float*)d_in[21];
  const float* Wd  = (const float*)d_in[22]; const float* bd  = (const float*)d_in[23];
  const float* Wo  = (const float*)d_in[24]; const float* bo  = (const float*)d_in[25];
  float* out = (float*)d_out;

  const int N = in_sizes[0] / 128;
  const int E = in_sizes[2] / 2;
  const int G1 = (N + GS - 1) >> GSH;
  const int G  = 2 * G1;

  char* ws = (char*)d_ws;
  size_t off = 0;
  auto alloc = [&](size_t bytes) -> void* {
    void* ptr = ws + off;
    off += (bytes + 255) & ~(size_t)255;
    return ptr;
  };
  float* h0   = (float*)alloc((size_t)N * 128 * sizeof(float));
  float* h1   = (float*)alloc((size_t)N * 128 * sizeof(float));
  float* ag0  = (float*)alloc((size_t)N * 128 * sizeof(float));
  float* ag1  = (float*)alloc((size_t)N * 128 * sizeof(float));
  int* pairs  = (int*)alloc((size_t)G * SCAP * sizeof(int));
  int* offs   = (int*)alloc((size_t)(2 * N) * sizeof(int));
  int* counts = (int*)alloc((size_t)(2 * N) * sizeof(int));
  int* gcur   = (int*)alloc((size_t)(G + 8) * sizeof(int));
  float* pbuf = (float*)alloc(2 * 64 * 64 * sizeof(float));
  (void)ws_size; (void)n_in; (void)out_size;

  // ---- CSR build ----
  hipMemsetAsync(gcur, 0, (size_t)(G + 8) * sizeof(int), stream);
  {
    dim3 gb((E + 4095) / 4096, 2);
    bin_kernel<<<gb, 1024, 0, stream>>>(e1, e1 + E, e2, e2 + E, gcur, pairs, E, G1);
    dim3 gr(G1, 2);
    refine_kernel<<<gr, 1024, 0, stream>>>(gcur, pairs, offs, counts, N, G1);
  }

  const int* offs0 = offs;       const int* cnts0 = counts;
  const int* offs1 = offs + N;   const int* cnts1 = counts + N;

  // layer 1
  {
    dim3 gg((N + 31) / 32, 2);
    gemm2_kernel<128><<<gg, 256, 0, stream>>>(x1, x2, W1a, W2a, b1a, b2a, h0, h1, N);
  }
  {
    dim3 ga((N + 3) / 4, 2);
    agg128_kernel<<<ga, 256, 0, stream>>>(h0, offs0, cnts0, pairs, g1a, be1a, ag0, N);
    agg128_kernel<<<ga, 256, 0, stream>>>(h1, offs1, cnts1, pairs, g2a, be2a, ag1, N);
  }
  // layer 2
  {
    dim3 gg((N + 31) / 32, 2);
    gemm2_kernel<64><<<gg, 256, 0, stream>>>(ag0, ag1, W1b, W2b, b1b, b2b, h0, h1, N);
  }
  agg64_kernel<<<(N + 3) / 4, 256, 0, stream>>>(h0, offs0, cnts0, pairs, g1b, be1b, ag0, N);
  agg64_kernel<<<(N + 3) / 4, 256, 0, stream>>>(h1, offs1, cnts1, pairs, g2b, be2b, ag1, N);
  // pool + head
  {
    dim3 gp(64, 2);
    pool2_kernel<<<gp, 1024, 0, stream>>>(ag0, ag1, seg1, seg2, pbuf, N);
  }
  head_kernel<<<1, 512, 0, stream>>>(pbuf, Wd, bd, Wo, bo, out);
}

// Round 14
// 355.113 us; speedup vs baseline: 2.3723x; 1.0331x over previous
//
#include <hip/hip_runtime.h>
#include <math.h>

#define GS    512   // nodes per group
#define GSH   9
#define NGMAX 128   // max groups per branch (G1=98 for N=50000)
#define FCAP  48    // LDS FIFO capacity per group per round
#define SCAP  10240 // group region capacity

// ---------------- pass 1: bin edges into 512-node groups ----------------

__global__ __launch_bounds__(1024) void bin_kernel(
    const int* __restrict__ s1, const int* __restrict__ d1,
    const int* __restrict__ s2, const int* __restrict__ d2,
    int* __restrict__ gcur, int* __restrict__ pairs, int E, int G1) {
  __shared__ int fifo[NGMAX][FCAP];
  __shared__ int fcnt[NGMAX];
  __shared__ int fbase[NGMAX];
  __shared__ int fpre[NGMAX + 1];
  const int* src = blockIdx.y ? s2 : s1;
  const int* dst = blockIdx.y ? d2 : d1;
  int gboff = blockIdx.y * G1;
  int tid = threadIdx.x;
  if (tid < NGMAX) fcnt[tid] = 0;
  __syncthreads();
  int e0 = blockIdx.x * 4096;
  for (int r = 0; r < 4; ++r) {
    int e = e0 + r * 1024 + tid;
    if (e < E) {
      int s = src[e], d = dst[e];
      int g = d >> GSH;
      int pk = s | ((d & (GS - 1)) << 17);
      int pos = atomicAdd(&fcnt[g], 1);
      if (pos < FCAP) fifo[g][pos] = pk;
      else {
        int gp = atomicAdd(&gcur[gboff + g], 1);
        pairs[(size_t)(gboff + g) * SCAP + gp] = pk;
      }
    }
    __syncthreads();
    if (tid < G1) {
      int c = fcnt[tid];
      if (c > FCAP) c = FCAP;
      fcnt[tid] = c;
      fbase[tid] = (c > 0) ? atomicAdd(&gcur[gboff + tid], c) : 0;
    }
    __syncthreads();
    if (tid == 0) {
      int acc = 0;
      for (int i = 0; i < G1; ++i) { fpre[i] = acc; acc += fcnt[i]; }
      fpre[G1] = acc;
    }
    __syncthreads();
    int T = fpre[G1];
    for (int t = tid; t < T; t += 1024) {
      int lo = 0, hi = G1;
      while (hi - lo > 1) { int mid = (lo + hi) >> 1; if (fpre[mid] <= t) lo = mid; else hi = mid; }
      int idx = t - fpre[lo];
      pairs[(size_t)(gboff + lo) * SCAP + fbase[lo] + idx] = fifo[lo][idx];
    }
    __syncthreads();
    if (tid < NGMAX) fcnt[tid] = 0;
    __syncthreads();
  }
}

// ---------------- pass 2: per-group node CSR, in-place ----------------

__global__ __launch_bounds__(1024) void refine_kernel(
    const int* __restrict__ gcur, int* __restrict__ pairs,
    int* __restrict__ offs, int* __restrict__ counts, int N, int G1) {
  __shared__ int stg[SCAP];
  __shared__ int hist[GS];
  __shared__ int excl[GS];
  __shared__ int wtot[8];
  int gl = blockIdx.x, br = blockIdx.y;
  int g = br * G1 + gl;
  size_t rbase = (size_t)g * SCAP;
  int rcnt = gcur[g];
  if (rcnt > SCAP) rcnt = SCAP;
  int tid = threadIdx.x;
  if (tid < GS) hist[tid] = 0;
  __syncthreads();
  for (int i = tid; i < rcnt; i += 1024) {
    int pk = pairs[rbase + i];
    stg[i] = pk;
    atomicAdd(&hist[pk >> 17], 1);
  }
  __syncthreads();
  if (tid < GS) {
    int lane = tid & 63, wv = tid >> 6;
    int v = hist[tid];
    int inc = v;
    #pragma unroll
    for (int off = 1; off < 64; off <<= 1) {
      int t = __shfl_up(inc, off);
      if (lane >= off) inc += t;
    }
    excl[tid] = inc - v;
    if (lane == 63) wtot[wv] = inc;
  }
  __syncthreads();
  if (tid == 0) {
    int a = 0;
    #pragma unroll
    for (int w = 0; w < 8; ++w) { int t = wtot[w]; wtot[w] = a; a += t; }
  }
  __syncthreads();
  if (tid < GS) excl[tid] += wtot[tid >> 6];
  __syncthreads();
  int node0 = gl * GS;
  int nloc = N - node0; if (nloc > GS) nloc = GS;
  for (int j = tid; j < nloc; j += 1024) {
    offs[br * N + node0 + j] = (int)rbase + excl[j];
    counts[br * N + node0 + j] = hist[j];
  }
  __syncthreads();
  for (int i = tid; i < rcnt; i += 1024) {
    int pk = stg[i];
    int pos = atomicAdd(&excl[pk >> 17], 1);
    pairs[rbase + pos] = pk & 0x1FFFF;
  }
}

// ---------------- GEMM both branches: BM=64, 128 threads, R x 8-col thread tile ----------------
// Y[br][nrows,COUT] = X[br] @ W[br] + b[br]. 8 cols/thread halves LDS bytes per FMA
// (R10 kernel was LDS-read-throughput bound at 46% VALUBusy).

template <int COUT>
__global__ __launch_bounds__(128, 2) void gemm2_kernel(
    const float* __restrict__ X0, const float* __restrict__ X1,
    const float* __restrict__ W0, const float* __restrict__ W1,
    const float* __restrict__ bias0, const float* __restrict__ bias1,
    float* __restrict__ Y0, float* __restrict__ Y1, int nrows) {
  constexpr int CG = COUT / 8;     // col groups of 8: 16 / 8
  constexpr int RG = 128 / CG;     // row groups: 8 / 16
  constexpr int BM = 64;
  constexpr int RPT = BM / RG;     // rows/thread: 8 / 4
  const float* X = blockIdx.y ? X1 : X0;
  const float* W = blockIdx.y ? W1 : W0;
  const float* bias = blockIdx.y ? bias1 : bias0;
  float* Y = blockIdx.y ? Y1 : Y0;
  __shared__ float xs[BM][132];
  int tid = threadIdx.x;
  int block_row = blockIdx.x * BM;
  for (int i = tid; i < BM * 32; i += 128) {
    int r = i >> 5, c4 = i & 31;
    int gr = block_row + r;
    float4 v = make_float4(0.f, 0.f, 0.f, 0.f);
    if (gr < nrows) v = reinterpret_cast<const float4*>(X + (size_t)gr * 128)[c4];
    *reinterpret_cast<float4*>(&xs[r][c4 * 4]) = v;
  }
  __syncthreads();
  int c0 = (tid % CG) * 8;
  int r0 = (tid / CG) * RPT;
  float acc[RPT][8] = {};
  for (int k = 0; k < 128; k += 4) {
    float4 wa[4], wb[4];
    #pragma unroll
    for (int kk = 0; kk < 4; ++kk) {
      wa[kk] = *reinterpret_cast<const float4*>(&W[(k + kk) * COUT + c0]);
      wb[kk] = *reinterpret_cast<const float4*>(&W[(k + kk) * COUT + c0 + 4]);
    }
    #pragma unroll
    for (int i = 0; i < RPT; ++i) {
      float4 x = *reinterpret_cast<const float4*>(&xs[r0 + i][k]);
      #pragma unroll
      for (int kk = 0; kk < 4; ++kk) {
        float xv = (kk == 0) ? x.x : (kk == 1) ? x.y : (kk == 2) ? x.z : x.w;
        acc[i][0] = fmaf(xv, wa[kk].x, acc[i][0]);
        acc[i][1] = fmaf(xv, wa[kk].y, acc[i][1]);
        acc[i][2] = fmaf(xv, wa[kk].z, acc[i][2]);
        acc[i][3] = fmaf(xv, wa[kk].w, acc[i][3]);
        acc[i][4] = fmaf(xv, wb[kk].x, acc[i][4]);
        acc[i][5] = fmaf(xv, wb[kk].y, acc[i][5]);
        acc[i][6] = fmaf(xv, wb[kk].z, acc[i][6]);
        acc[i][7] = fmaf(xv, wb[kk].w, acc[i][7]);
      }
    }
  }
  float4 bva = *reinterpret_cast<const float4*>(&bias[c0]);
  float4 bvb = *reinterpret_cast<const float4*>(&bias[c0 + 4]);
  #pragma unroll
  for (int i = 0; i < RPT; ++i) {
    int gr = block_row + r0 + i;
    if (gr < nrows) {
      float4 oa, ob;
      oa.x = acc[i][0] + bva.x; oa.y = acc[i][1] + bva.y;
      oa.z = acc[i][2] + bva.z; oa.w = acc[i][3] + bva.w;
      ob.x = acc[i][4] + bvb.x; ob.y = acc[i][5] + bvb.y;
      ob.z = acc[i][6] + bvb.z; ob.w = acc[i][7] + bvb.w;
      *reinterpret_cast<float4*>(&Y[(size_t)gr * COUT + c0]) = oa;
      *reinterpret_cast<float4*>(&Y[(size_t)gr * COUT + c0 + 4]) = ob;
    }
  }
}

// ---------------- agg C=128, column-split (blockIdx.y = col half) ----------------

__global__ __launch_bounds__(256) void agg128_kernel(
    const float* __restrict__ h, const int* __restrict__ offs,
    const int* __restrict__ counts, const int* __restrict__ csr_src,
    const float* __restrict__ gamma, const float* __restrict__ beta,
    float* __restrict__ out, int n) {
  int node = blockIdx.x * 4 + (threadIdx.x >> 6);
  if (node >= n) return;
  node = __builtin_amdgcn_readfirstlane(node);
  int ch = blockIdx.y;
  int lane = threadIdx.x & 63;
  int half = lane >> 5;
  int l5 = lane & 31;
  const float* hh = h + ch * 64;
  int beg = offs[node], cnt = counts[node];
  const int* lp = csr_src + beg;
  float a0 = 0.f, a1 = 0.f;
  for (int base = 0; base < cnt; base += 64) {
    int rem = cnt - base;
    int m = rem < 64 ? rem : 64;
    int idx = lp[base + (lane < m ? lane : m - 1)];
    int mfull = m & ~15;
    int j = 0;
    for (; j < mfull; j += 16) {
      float2 v[8];
      #pragma unroll
      for (int u = 0; u < 8; ++u) {
        int s = __shfl(idx, j + 2 * u + half);
        v[u] = *reinterpret_cast<const float2*>(hh + (size_t)s * 128 + l5 * 2);
      }
      #pragma unroll
      for (int u = 0; u < 8; ++u) { a0 += v[u].x; a1 += v[u].y; }
    }
    if (j < m) {
      float2 v[8];
      #pragma unroll
      for (int u = 0; u < 8; ++u) {
        int ed = j + 2 * u + half;
        int s = __shfl(idx, ed < m ? ed : m - 1);
        v[u] = *reinterpret_cast<const float2*>(hh + (size_t)s * 128 + l5 * 2);
      }
      #pragma unroll
      for (int u = 0; u < 8; ++u) {
        bool ok = (j + 2 * u + half) < m;
        a0 += ok ? v[u].x : 0.f;
        a1 += ok ? v[u].y : 0.f;
      }
    }
  }
  a0 += __shfl_xor(a0, 32);
  a1 += __shfl_xor(a1, 32);
  const float inv = 1.0f / sqrtf(1.0f + 1.0e-3f);
  if (half == 0) {
    float2 g = reinterpret_cast<const float2*>(gamma + ch * 64)[l5];
    float2 b = reinterpret_cast<const float2*>(beta + ch * 64)[l5];
    float2 o;
    o.x = fmaxf(fmaf(a0, g.x * inv, b.x), 0.f);
    o.y = fmaxf(fmaf(a1, g.y * inv, b.y), 0.f);
    *reinterpret_cast<float2*>(out + (size_t)node * 128 + ch * 64 + l5 * 2) = o;
  }
}

// ---------------- agg C=64 ----------------

__global__ __launch_bounds__(256) void agg64_kernel(
    const float* __restrict__ h, const int* __restrict__ offs,
    const int* __restrict__ counts, const int* __restrict__ csr_src,
    const float* __restrict__ gamma, const float* __restrict__ beta,
    float* __restrict__ out, int n) {
  int node = blockIdx.x * 4 + (threadIdx.x >> 6);
  if (node >= n) return;
  node = __builtin_amdgcn_readfirstlane(node);
  int lane = threadIdx.x & 63;
  int half = lane >> 5;
  int l5 = lane & 31;
  int beg = offs[node], cnt = counts[node];
  const int* lp = csr_src + beg;
  float a0 = 0.f, a1 = 0.f;
  for (int base = 0; base < cnt; base += 64) {
    int rem = cnt - base;
    int m = rem < 64 ? rem : 64;
    int idx = lp[base + (lane < m ? lane : m - 1)];
    int mfull = m & ~15;
    int j = 0;
    for (; j < mfull; j += 16) {
      float2 v[8];
      #pragma unroll
      for (int u = 0; u < 8; ++u) {
        int s = __shfl(idx, j + 2 * u + half);
        v[u] = *reinterpret_cast<const float2*>(h + (size_t)s * 64 + l5 * 2);
      }
      #pragma unroll
      for (int u = 0; u < 8; ++u) { a0 += v[u].x; a1 += v[u].y; }
    }
    if (j < m) {
      float2 v[8];
      #pragma unroll
      for (int u = 0; u < 8; ++u) {
        int ed = j + 2 * u + half;
        int s = __shfl(idx, ed < m ? ed : m - 1);
        v[u] = *reinterpret_cast<const float2*>(h + (size_t)s * 64 + l5 * 2);
      }
      #pragma unroll
      for (int u = 0; u < 8; ++u) {
        bool ok = (j + 2 * u + half) < m;
        a0 += ok ? v[u].x : 0.f;
        a1 += ok ? v[u].y : 0.f;
      }
    }
  }
  a0 += __shfl_xor(a0, 32);
  a1 += __shfl_xor(a1, 32);
  const float inv = 1.0f / sqrtf(1.0f + 1.0e-3f);
  if (half == 0) {
    float2 g = reinterpret_cast<const float2*>(gamma)[l5];
    float2 b = reinterpret_cast<const float2*>(beta)[l5];
    float2 o;
    o.x = fmaxf(fmaf(a0, g.x * inv, b.x), 0.f);
    o.y = fmaxf(fmaf(a1, g.y * inv, b.y), 0.f);
    *reinterpret_cast<float2*>(out + (size_t)node * 64 + l5 * 2) = o;
  }
}

// ---------------- Segment mean pool, both branches ----------------

__global__ __launch_bounds__(1024) void pool2_kernel(
    const float* __restrict__ h0, const float* __restrict__ h1,
    const int* __restrict__ seg0, const int* __restrict__ seg1,
    float* __restrict__ p, int n) {
  const float* h = blockIdx.y ? h1 : h0;
  const int* seg = blockIdx.y ? seg1 : seg0;
  float* pb = p + blockIdx.y * 64 * 64;
  int g = blockIdx.x;
  int lo, hi;
  { int l = 0, r = n; while (l < r) { int m = (l + r) >> 1; if (seg[m] < g) l = m + 1; else r = m; } lo = l; }
  { int l = 0, r = n; while (l < r) { int m = (l + r) >> 1; if (seg[m] < g + 1) l = m + 1; else r = m; } hi = l; }
  int c = threadIdx.x & 63;
  int sub = threadIdx.x >> 6;
  float acc = 0.f;
  for (int i = lo + sub; i < hi; i += 16) acc += h[(size_t)i * 64 + c];
  __shared__ float red[16][64];
  red[sub][c] = acc;
  __syncthreads();
  if (sub == 0) {
    float s = 0.f;
    #pragma unroll
    for (int k = 0; k < 16; ++k) s += red[k][c];
    float cnt = (float)(hi - lo);
    pb[g * 64 + c] = s / fmaxf(cnt, 1.0f);
  }
}

// ---------------- Head ----------------

__global__ __launch_bounds__(512) void head_kernel(const float* __restrict__ p,
                                                   const float* __restrict__ Wd,
                                                   const float* __restrict__ bd,
                                                   const float* __restrict__ Wo,
                                                   const float* __restrict__ bo,
                                                   float* __restrict__ out) {
  __shared__ float cur[64][128];
  __shared__ float nxt[64][128];
  int tid = threadIdx.x;
  const float* p1 = p;
  const float* p2 = p + 64 * 64;
  for (int i = tid; i < 64 * 128; i += 512) {
    int r = i >> 7, c = i & 127;
    cur[r][c] = (c < 64) ? p1[r * 64 + c] : p2[r * 64 + (c - 64)];
  }
  __syncthreads();
  int c0 = (tid & 31) * 4;
  int r0 = (tid >> 5) * 4;
  for (int layer = 0; layer < 2; ++layer) {
    float acc[4][4] = {};
    #pragma unroll 4
    for (int k = 0; k < 128; ++k) {
      float4 w = *reinterpret_cast<const float4*>(&Wd[k * 128 + c0]);
      #pragma unroll
      for (int i = 0; i < 4; ++i) {
        float x = cur[r0 + i][k];
        acc[i][0] = fmaf(x, w.x, acc[i][0]);
        acc[i][1] = fmaf(x, w.y, acc[i][1]);
        acc[i][2] = fmaf(x, w.z, acc[i][2]);
        acc[i][3] = fmaf(x, w.w, acc[i][3]);
      }
    }
    float4 bv = *reinterpret_cast<const float4*>(&bd[c0]);
    __syncthreads();
    #pragma unroll
    for (int i = 0; i < 4; ++i) {
      float4 o;
      o.x = fmaxf(acc[i][0] + bv.x, 0.f);
      o.y = fmaxf(acc[i][1] + bv.y, 0.f);
      o.z = fmaxf(acc[i][2] + bv.z, 0.f);
      o.w = fmaxf(acc[i][3] + bv.w, 0.f);
      *reinterpret_cast<float4*>(&nxt[r0 + i][c0]) = o;
    }
    __syncthreads();
    for (int i = tid; i < 64 * 128; i += 512) (&cur[0][0])[i] = (&nxt[0][0])[i];
    __syncthreads();
  }
  int wv = tid >> 6, lane = tid & 63;
  for (int r = wv; r < 64; r += 8) {
    float v = cur[r][lane] * Wo[lane] + cur[r][64 + lane] * Wo[64 + lane];
    #pragma unroll
    for (int off = 32; off; off >>= 1) v += __shfl_down(v, off);
    if (lane == 0) out[r] = 1.0f / (1.0f + expf(-(v + bo[0])));
  }
}

// ---------------- launch ----------------

extern "C" void kernel_launch(void* const* d_in, const int* in_sizes, int n_in,
                              void* d_out, int out_size, void* d_ws, size_t ws_size,
                              hipStream_t stream) {
  const float* x1  = (const float*)d_in[0];
  const float* x2  = (const float*)d_in[1];
  const int* e1    = (const int*)d_in[2];
  const int* e2    = (const int*)d_in[3];
  const int* seg1  = (const int*)d_in[4];
  const int* seg2  = (const int*)d_in[5];
  const float* W1a = (const float*)d_in[6];  const float* b1a = (const float*)d_in[7];
  const float* g1a = (const float*)d_in[8];  const float* be1a = (const float*)d_in[9];
  const float* W1b = (const float*)d_in[10]; const float* b1b = (const float*)d_in[11];
  const float* g1b = (const float*)d_in[12]; const float* be1b = (const float*)d_in[13];
  const float* W2a = (const float*)d_in[14]; const float* b2a = (const float*)d_in[15];
  const float* g2a = (const float*)d_in[16]; const float* be2a = (const float*)d_in[17];
  const float* W2b = (const float*)d_in[18]; const float* b2b = (const float*)d_in[19];
  const float* g2b = (const float*)d_in[20]; const float* be2b = (const float*)d_in[21];
  const float* Wd  = (const float*)d_in[22]; const float* bd  = (const float*)d_in[23];
  const float* Wo  = (const float*)d_in[24]; const float* bo  = (const float*)d_in[25];
  float* out = (float*)d_out;

  const int N = in_sizes[0] / 128;
  const int E = in_sizes[2] / 2;
  const int G1 = (N + GS - 1) >> GSH;
  const int G  = 2 * G1;

  char* ws = (char*)d_ws;
  size_t off = 0;
  auto alloc = [&](size_t bytes) -> void* {
    void* ptr = ws + off;
    off += (bytes + 255) & ~(size_t)255;
    return ptr;
  };
  float* h0   = (float*)alloc((size_t)N * 128 * sizeof(float));
  float* h1   = (float*)alloc((size_t)N * 128 * sizeof(float));
  float* ag0  = (float*)alloc((size_t)N * 128 * sizeof(float));
  float* ag1  = (float*)alloc((size_t)N * 128 * sizeof(float));
  int* pairs  = (int*)alloc((size_t)G * SCAP * sizeof(int));
  int* offs   = (int*)alloc((size_t)(2 * N) * sizeof(int));
  int* counts = (int*)alloc((size_t)(2 * N) * sizeof(int));
  int* gcur   = (int*)alloc((size_t)(G + 8) * sizeof(int));
  float* pbuf = (float*)alloc(2 * 64 * 64 * sizeof(float));
  (void)ws_size; (void)n_in; (void)out_size;

  // ---- CSR build ----
  hipMemsetAsync(gcur, 0, (size_t)(G + 8) * sizeof(int), stream);
  {
    dim3 gb((E + 4095) / 4096, 2);
    bin_kernel<<<gb, 1024, 0, stream>>>(e1, e1 + E, e2, e2 + E, gcur, pairs, E, G1);
    dim3 gr(G1, 2);
    refine_kernel<<<gr, 1024, 0, stream>>>(gcur, pairs, offs, counts, N, G1);
  }

  const int* offs0 = offs;       const int* cnts0 = counts;
  const int* offs1 = offs + N;   const int* cnts1 = counts + N;

  // layer 1
  {
    dim3 gg((N + 63) / 64, 2);
    gemm2_kernel<128><<<gg, 128, 0, stream>>>(x1, x2, W1a, W2a, b1a, b2a, h0, h1, N);
  }
  {
    dim3 ga((N + 3) / 4, 2);
    agg128_kernel<<<ga, 256, 0, stream>>>(h0, offs0, cnts0, pairs, g1a, be1a, ag0, N);
    agg128_kernel<<<ga, 256, 0, stream>>>(h1, offs1, cnts1, pairs, g2a, be2a, ag1, N);
  }
  // layer 2
  {
    dim3 gg((N + 63) / 64, 2);
    gemm2_kernel<64><<<gg, 128, 0, stream>>>(ag0, ag1, W1b, W2b, b1b, b2b, h0, h1, N);
  }
  agg64_kernel<<<(N + 3) / 4, 256, 0, stream>>>(h0, offs0, cnts0, pairs, g1b, be1b, ag0, N);
  agg64_kernel<<<(N + 3) / 4, 256, 0, stream>>>(h1, offs1, cnts1, pairs, g2b, be2b, ag1, N);
  // pool + head
  {
    dim3 gp(64, 2);
    pool2_kernel<<<gp, 1024, 0, stream>>>(ag0, ag1, seg1, seg2, pbuf, N);
  }
  head_kernel<<<1, 512, 0, stream>>>(pbuf, Wd, bd, Wo, bo, out);
}

// Round 15
// 330.104 us; speedup vs baseline: 2.5520x; 1.0758x over previous
//
#include <hip/hip_runtime.h>
#include <math.h>

#define GS    512   // nodes per group
#define GSH   9
#define NGMAX 128   // max groups per branch (G1=98 for N=50000)
#define FCAP  48    // LDS FIFO capacity per group per round
#define SCAP  10240 // group region capacity

// ---------------- pass 1: bin edges into 512-node groups ----------------

__global__ __launch_bounds__(1024) void bin_kernel(
    const int* __restrict__ s1, const int* __restrict__ d1,
    const int* __restrict__ s2, const int* __restrict__ d2,
    int* __restrict__ gcur, int* __restrict__ pairs, int E, int G1) {
  __shared__ int fifo[NGMAX][FCAP];
  __shared__ int fcnt[NGMAX];
  __shared__ int fbase[NGMAX];
  __shared__ int fpre[NGMAX + 1];
  const int* src = blockIdx.y ? s2 : s1;
  const int* dst = blockIdx.y ? d2 : d1;
  int gboff = blockIdx.y * G1;
  int tid = threadIdx.x;
  if (tid < NGMAX) fcnt[tid] = 0;
  __syncthreads();
  int e0 = blockIdx.x * 4096;
  for (int r = 0; r < 4; ++r) {
    int e = e0 + r * 1024 + tid;
    if (e < E) {
      int s = src[e], d = dst[e];
      int g = d >> GSH;
      int pk = s | ((d & (GS - 1)) << 17);
      int pos = atomicAdd(&fcnt[g], 1);
      if (pos < FCAP) fifo[g][pos] = pk;
      else {
        int gp = atomicAdd(&gcur[gboff + g], 1);
        pairs[(size_t)(gboff + g) * SCAP + gp] = pk;
      }
    }
    __syncthreads();
    if (tid < G1) {
      int c = fcnt[tid];
      if (c > FCAP) c = FCAP;
      fcnt[tid] = c;
      fbase[tid] = (c > 0) ? atomicAdd(&gcur[gboff + tid], c) : 0;
    }
    __syncthreads();
    if (tid == 0) {
      int acc = 0;
      for (int i = 0; i < G1; ++i) { fpre[i] = acc; acc += fcnt[i]; }
      fpre[G1] = acc;
    }
    __syncthreads();
    int T = fpre[G1];
    for (int t = tid; t < T; t += 1024) {
      int lo = 0, hi = G1;
      while (hi - lo > 1) { int mid = (lo + hi) >> 1; if (fpre[mid] <= t) lo = mid; else hi = mid; }
      int idx = t - fpre[lo];
      pairs[(size_t)(gboff + lo) * SCAP + fbase[lo] + idx] = fifo[lo][idx];
    }
    __syncthreads();
    if (tid < NGMAX) fcnt[tid] = 0;
    __syncthreads();
  }
}

// ---------------- pass 2: per-group node CSR, in-place ----------------

__global__ __launch_bounds__(1024) void refine_kernel(
    const int* __restrict__ gcur, int* __restrict__ pairs,
    int* __restrict__ offs, int* __restrict__ counts, int N, int G1) {
  __shared__ int stg[SCAP];
  __shared__ int hist[GS];
  __shared__ int excl[GS];
  __shared__ int wtot[8];
  int gl = blockIdx.x, br = blockIdx.y;
  int g = br * G1 + gl;
  size_t rbase = (size_t)g * SCAP;
  int rcnt = gcur[g];
  if (rcnt > SCAP) rcnt = SCAP;
  int tid = threadIdx.x;
  if (tid < GS) hist[tid] = 0;
  __syncthreads();
  for (int i = tid; i < rcnt; i += 1024) {
    int pk = pairs[rbase + i];
    stg[i] = pk;
    atomicAdd(&hist[pk >> 17], 1);
  }
  __syncthreads();
  if (tid < GS) {
    int lane = tid & 63, wv = tid >> 6;
    int v = hist[tid];
    int inc = v;
    #pragma unroll
    for (int off = 1; off < 64; off <<= 1) {
      int t = __shfl_up(inc, off);
      if (lane >= off) inc += t;
    }
    excl[tid] = inc - v;
    if (lane == 63) wtot[wv] = inc;
  }
  __syncthreads();
  if (tid == 0) {
    int a = 0;
    #pragma unroll
    for (int w = 0; w < 8; ++w) { int t = wtot[w]; wtot[w] = a; a += t; }
  }
  __syncthreads();
  if (tid < GS) excl[tid] += wtot[tid >> 6];
  __syncthreads();
  int node0 = gl * GS;
  int nloc = N - node0; if (nloc > GS) nloc = GS;
  for (int j = tid; j < nloc; j += 1024) {
    offs[br * N + node0 + j] = (int)rbase + excl[j];
    counts[br * N + node0 + j] = hist[j];
  }
  __syncthreads();
  for (int i = tid; i < rcnt; i += 1024) {
    int pk = stg[i];
    int pos = atomicAdd(&excl[pk >> 17], 1);
    pairs[rbase + pos] = pk & 0x1FFFF;
  }
}

// ---------------- GEMM both branches: R10 config, unpadded xs = 32KB -> 5 blocks/CU ----------------
// Lanes 0-31 of a wave read the same xs row (LDS broadcast) so no pad needed.

template <int COUT>
__global__ __launch_bounds__(256, 2) void gemm2_kernel(
    const float* __restrict__ X0, const float* __restrict__ X1,
    const float* __restrict__ W0, const float* __restrict__ W1,
    const float* __restrict__ bias0, const float* __restrict__ bias1,
    float* __restrict__ Y0, float* __restrict__ Y1, int nrows) {
  constexpr int CG = COUT / 4;
  constexpr int RG = 256 / CG;
  constexpr int BM = 64;
  constexpr int RPT = BM / RG;
  const float* X = blockIdx.y ? X1 : X0;
  const float* W = blockIdx.y ? W1 : W0;
  const float* bias = blockIdx.y ? bias1 : bias0;
  float* Y = blockIdx.y ? Y1 : Y0;
  __shared__ float xs[BM][128];
  int tid = threadIdx.x;
  int block_row = blockIdx.x * BM;
  for (int i = tid; i < BM * 32; i += 256) {
    int r = i >> 5, c4 = i & 31;
    int gr = block_row + r;
    float4 v = make_float4(0.f, 0.f, 0.f, 0.f);
    if (gr < nrows) v = reinterpret_cast<const float4*>(X + (size_t)gr * 128)[c4];
    *reinterpret_cast<float4*>(&xs[r][c4 * 4]) = v;
  }
  __syncthreads();
  int c0 = (tid % CG) * 4;
  int r0 = (tid / CG) * RPT;
  float acc[RPT][4] = {};
  #pragma unroll 2
  for (int k = 0; k < 128; k += 4) {
    float4 w0 = *reinterpret_cast<const float4*>(&W[(k + 0) * COUT + c0]);
    float4 w1 = *reinterpret_cast<const float4*>(&W[(k + 1) * COUT + c0]);
    float4 w2 = *reinterpret_cast<const float4*>(&W[(k + 2) * COUT + c0]);
    float4 w3 = *reinterpret_cast<const float4*>(&W[(k + 3) * COUT + c0]);
    #pragma unroll
    for (int i = 0; i < RPT; ++i) {
      float4 x = *reinterpret_cast<const float4*>(&xs[r0 + i][k]);
      acc[i][0] = fmaf(x.x, w0.x, acc[i][0]);
      acc[i][1] = fmaf(x.x, w0.y, acc[i][1]);
      acc[i][2] = fmaf(x.x, w0.z, acc[i][2]);
      acc[i][3] = fmaf(x.x, w0.w, acc[i][3]);
      acc[i][0] = fmaf(x.y, w1.x, acc[i][0]);
      acc[i][1] = fmaf(x.y, w1.y, acc[i][1]);
      acc[i][2] = fmaf(x.y, w1.z, acc[i][2]);
      acc[i][3] = fmaf(x.y, w1.w, acc[i][3]);
      acc[i][0] = fmaf(x.z, w2.x, acc[i][0]);
      acc[i][1] = fmaf(x.z, w2.y, acc[i][1]);
      acc[i][2] = fmaf(x.z, w2.z, acc[i][2]);
      acc[i][3] = fmaf(x.z, w2.w, acc[i][3]);
      acc[i][0] = fmaf(x.w, w3.x, acc[i][0]);
      acc[i][1] = fmaf(x.w, w3.y, acc[i][1]);
      acc[i][2] = fmaf(x.w, w3.z, acc[i][2]);
      acc[i][3] = fmaf(x.w, w3.w, acc[i][3]);
    }
  }
  float4 bv = *reinterpret_cast<const float4*>(&bias[c0]);
  #pragma unroll
  for (int i = 0; i < RPT; ++i) {
    int gr = block_row + r0 + i;
    if (gr < nrows) {
      float4 o;
      o.x = acc[i][0] + bv.x; o.y = acc[i][1] + bv.y;
      o.z = acc[i][2] + bv.z; o.w = acc[i][3] + bv.w;
      *reinterpret_cast<float4*>(&Y[(size_t)gr * COUT + c0]) = o;
    }
  }
}

// ---------------- agg C=128, both branches + col halves in one dispatch ----------------
// blockIdx.y = br*2 + ch: y dispatches in order -> phases (br0ch0, br0ch1, br1ch0,
// br1ch1), each with a 12.8MB instantaneous table working set.

__global__ __launch_bounds__(256) void agg128_kernel(
    const float* __restrict__ h0, const float* __restrict__ h1,
    const int* __restrict__ offs, const int* __restrict__ counts,
    const int* __restrict__ csr_src,
    const float* __restrict__ ga0, const float* __restrict__ be0,
    const float* __restrict__ ga1, const float* __restrict__ be1,
    float* __restrict__ o0, float* __restrict__ o1, int n) {
  int node = blockIdx.x * 4 + (threadIdx.x >> 6);
  if (node >= n) return;
  node = __builtin_amdgcn_readfirstlane(node);
  int br = blockIdx.y >> 1, ch = blockIdx.y & 1;
  const float* h = br ? h1 : h0;
  const float* gamma = br ? ga1 : ga0;
  const float* beta = br ? be1 : be0;
  float* out = br ? o1 : o0;
  int lane = threadIdx.x & 63;
  int half = lane >> 5;
  int l5 = lane & 31;
  const float* hh = h + ch * 64;
  int beg = offs[br * n + node], cnt = counts[br * n + node];
  const int* lp = csr_src + beg;
  float a0 = 0.f, a1 = 0.f;
  for (int base = 0; base < cnt; base += 64) {
    int rem = cnt - base;
    int m = rem < 64 ? rem : 64;
    int idx = lp[base + (lane < m ? lane : m - 1)];
    int mfull = m & ~15;
    int j = 0;
    for (; j < mfull; j += 16) {
      float2 v[8];
      #pragma unroll
      for (int u = 0; u < 8; ++u) {
        int s = __shfl(idx, j + 2 * u + half);
        v[u] = *reinterpret_cast<const float2*>(hh + (size_t)s * 128 + l5 * 2);
      }
      #pragma unroll
      for (int u = 0; u < 8; ++u) { a0 += v[u].x; a1 += v[u].y; }
    }
    if (j < m) {
      float2 v[8];
      #pragma unroll
      for (int u = 0; u < 8; ++u) {
        int ed = j + 2 * u + half;
        int s = __shfl(idx, ed < m ? ed : m - 1);
        v[u] = *reinterpret_cast<const float2*>(hh + (size_t)s * 128 + l5 * 2);
      }
      #pragma unroll
      for (int u = 0; u < 8; ++u) {
        bool ok = (j + 2 * u + half) < m;
        a0 += ok ? v[u].x : 0.f;
        a1 += ok ? v[u].y : 0.f;
      }
    }
  }
  a0 += __shfl_xor(a0, 32);
  a1 += __shfl_xor(a1, 32);
  const float inv = 1.0f / sqrtf(1.0f + 1.0e-3f);
  if (half == 0) {
    float2 g = reinterpret_cast<const float2*>(gamma + ch * 64)[l5];
    float2 b = reinterpret_cast<const float2*>(beta + ch * 64)[l5];
    float2 o;
    o.x = fmaxf(fmaf(a0, g.x * inv, b.x), 0.f);
    o.y = fmaxf(fmaf(a1, g.y * inv, b.y), 0.f);
    *reinterpret_cast<float2*>(out + (size_t)node * 128 + ch * 64 + l5 * 2) = o;
  }
}

// ---------------- agg C=64, both branches in one dispatch (blockIdx.y = br) ----------------

__global__ __launch_bounds__(256) void agg64_kernel(
    const float* __restrict__ h0, const float* __restrict__ h1,
    const int* __restrict__ offs, const int* __restrict__ counts,
    const int* __restrict__ csr_src,
    const float* __restrict__ ga0, const float* __restrict__ be0,
    const float* __restrict__ ga1, const float* __restrict__ be1,
    float* __restrict__ o0, float* __restrict__ o1, int n) {
  int node = blockIdx.x * 4 + (threadIdx.x >> 6);
  if (node >= n) return;
  node = __builtin_amdgcn_readfirstlane(node);
  int br = blockIdx.y;
  const float* h = br ? h1 : h0;
  const float* gamma = br ? ga1 : ga0;
  const float* beta = br ? be1 : be0;
  float* out = br ? o1 : o0;
  int lane = threadIdx.x & 63;
  int half = lane >> 5;
  int l5 = lane & 31;
  int beg = offs[br * n + node], cnt = counts[br * n + node];
  const int* lp = csr_src + beg;
  float a0 = 0.f, a1 = 0.f;
  for (int base = 0; base < cnt; base += 64) {
    int rem = cnt - base;
    int m = rem < 64 ? rem : 64;
    int idx = lp[base + (lane < m ? lane : m - 1)];
    int mfull = m & ~15;
    int j = 0;
    for (; j < mfull; j += 16) {
      float2 v[8];
      #pragma unroll
      for (int u = 0; u < 8; ++u) {
        int s = __shfl(idx, j + 2 * u + half);
        v[u] = *reinterpret_cast<const float2*>(h + (size_t)s * 64 + l5 * 2);
      }
      #pragma unroll
      for (int u = 0; u < 8; ++u) { a0 += v[u].x; a1 += v[u].y; }
    }
    if (j < m) {
      float2 v[8];
      #pragma unroll
      for (int u = 0; u < 8; ++u) {
        int ed = j + 2 * u + half;
        int s = __shfl(idx, ed < m ? ed : m - 1);
        v[u] = *reinterpret_cast<const float2*>(h + (size_t)s * 64 + l5 * 2);
      }
      #pragma unroll
      for (int u = 0; u < 8; ++u) {
        bool ok = (j + 2 * u + half) < m;
        a0 += ok ? v[u].x : 0.f;
        a1 += ok ? v[u].y : 0.f;
      }
    }
  }
  a0 += __shfl_xor(a0, 32);
  a1 += __shfl_xor(a1, 32);
  const float inv = 1.0f / sqrtf(1.0f + 1.0e-3f);
  if (half == 0) {
    float2 g = reinterpret_cast<const float2*>(gamma)[l5];
    float2 b = reinterpret_cast<const float2*>(beta)[l5];
    float2 o;
    o.x = fmaxf(fmaf(a0, g.x * inv, b.x), 0.f);
    o.y = fmaxf(fmaf(a1, g.y * inv, b.y), 0.f);
    *reinterpret_cast<float2*>(out + (size_t)node * 64 + l5 * 2) = o;
  }
}

// ---------------- Segment mean pool, both branches ----------------

__global__ __launch_bounds__(1024) void pool2_kernel(
    const float* __restrict__ h0, const float* __restrict__ h1,
    const int* __restrict__ seg0, const int* __restrict__ seg1,
    float* __restrict__ p, int n) {
  const float* h = blockIdx.y ? h1 : h0;
  const int* seg = blockIdx.y ? seg1 : seg0;
  float* pb = p + blockIdx.y * 64 * 64;
  int g = blockIdx.x;
  int lo, hi;
  { int l = 0, r = n; while (l < r) { int m = (l + r) >> 1; if (seg[m] < g) l = m + 1; else r = m; } lo = l; }
  { int l = 0, r = n; while (l < r) { int m = (l + r) >> 1; if (seg[m] < g + 1) l = m + 1; else r = m; } hi = l; }
  int c = threadIdx.x & 63;
  int sub = threadIdx.x >> 6;
  float acc = 0.f;
  for (int i = lo + sub; i < hi; i += 16) acc += h[(size_t)i * 64 + c];
  __shared__ float red[16][64];
  red[sub][c] = acc;
  __syncthreads();
  if (sub == 0) {
    float s = 0.f;
    #pragma unroll
    for (int k = 0; k < 16; ++k) s += red[k][c];
    float cnt = (float)(hi - lo);
    pb[g * 64 + c] = s / fmaxf(cnt, 1.0f);
  }
}

// ---------------- Head ----------------

__global__ __launch_bounds__(512) void head_kernel(const float* __restrict__ p,
                                                   const float* __restrict__ Wd,
                                                   const float* __restrict__ bd,
                                                   const float* __restrict__ Wo,
                                                   const float* __restrict__ bo,
                                                   float* __restrict__ out) {
  __shared__ float cur[64][128];
  __shared__ float nxt[64][128];
  int tid = threadIdx.x;
  const float* p1 = p;
  const float* p2 = p + 64 * 64;
  for (int i = tid; i < 64 * 128; i += 512) {
    int r = i >> 7, c = i & 127;
    cur[r][c] = (c < 64) ? p1[r * 64 + c] : p2[r * 64 + (c - 64)];
  }
  __syncthreads();
  int c0 = (tid & 31) * 4;
  int r0 = (tid >> 5) * 4;
  for (int layer = 0; layer < 2; ++layer) {
    float acc[4][4] = {};
    #pragma unroll 4
    for (int k = 0; k < 128; ++k) {
      float4 w = *reinterpret_cast<const float4*>(&Wd[k * 128 + c0]);
      #pragma unroll
      for (int i = 0; i < 4; ++i) {
        float x = cur[r0 + i][k];
        acc[i][0] = fmaf(x, w.x, acc[i][0]);
        acc[i][1] = fmaf(x, w.y, acc[i][1]);
        acc[i][2] = fmaf(x, w.z, acc[i][2]);
        acc[i][3] = fmaf(x, w.w, acc[i][3]);
      }
    }
    float4 bv = *reinterpret_cast<const float4*>(&bd[c0]);
    __syncthreads();
    #pragma unroll
    for (int i = 0; i < 4; ++i) {
      float4 o;
      o.x = fmaxf(acc[i][0] + bv.x, 0.f);
      o.y = fmaxf(acc[i][1] + bv.y, 0.f);
      o.z = fmaxf(acc[i][2] + bv.z, 0.f);
      o.w = fmaxf(acc[i][3] + bv.w, 0.f);
      *reinterpret_cast<float4*>(&nxt[r0 + i][c0]) = o;
    }
    __syncthreads();
    for (int i = tid; i < 64 * 128; i += 512) (&cur[0][0])[i] = (&nxt[0][0])[i];
    __syncthreads();
  }
  int wv = tid >> 6, lane = tid & 63;
  for (int r = wv; r < 64; r += 8) {
    float v = cur[r][lane] * Wo[lane] + cur[r][64 + lane] * Wo[64 + lane];
    #pragma unroll
    for (int off = 32; off; off >>= 1) v += __shfl_down(v, off);
    if (lane == 0) out[r] = 1.0f / (1.0f + expf(-(v + bo[0])));
  }
}

// ---------------- launch ----------------

extern "C" void kernel_launch(void* const* d_in, const int* in_sizes, int n_in,
                              void* d_out, int out_size, void* d_ws, size_t ws_size,
                              hipStream_t stream) {
  const float* x1  = (const float*)d_in[0];
  const float* x2  = (const float*)d_in[1];
  const int* e1    = (const int*)d_in[2];
  const int* e2    = (const int*)d_in[3];
  const int* seg1  = (const int*)d_in[4];
  const int* seg2  = (const int*)d_in[5];
  const float* W1a = (const float*)d_in[6];  const float* b1a = (const float*)d_in[7];
  const float* g1a = (const float*)d_in[8];  const float* be1a = (const float*)d_in[9];
  const float* W1b = (const float*)d_in[10]; const float* b1b = (const float*)d_in[11];
  const float* g1b = (const float*)d_in[12]; const float* be1b = (const float*)d_in[13];
  const float* W2a = (const float*)d_in[14]; const float* b2a = (const float*)d_in[15];
  const float* g2a = (const float*)d_in[16]; const float* be2a = (const float*)d_in[17];
  const float* W2b = (const float*)d_in[18]; const float* b2b = (const float*)d_in[19];
  const float* g2b = (const float*)d_in[20]; const float* be2b = (const float*)d_in[21];
  const float* Wd  = (const float*)d_in[22]; const float* bd  = (const float*)d_in[23];
  const float* Wo  = (const float*)d_in[24]; const float* bo  = (const float*)d_in[25];
  float* out = (float*)d_out;

  const int N = in_sizes[0] / 128;
  const int E = in_sizes[2] / 2;
  const int G1 = (N + GS - 1) >> GSH;
  const int G  = 2 * G1;

  char* ws = (char*)d_ws;
  size_t off = 0;
  auto alloc = [&](size_t bytes) -> void* {
    void* ptr = ws + off;
    off += (bytes + 255) & ~(size_t)255;
    return ptr;
  };
  float* h0   = (float*)alloc((size_t)N * 128 * sizeof(float));
  float* h1   = (float*)alloc((size_t)N * 128 * sizeof(float));
  float* ag0  = (float*)alloc((size_t)N * 128 * sizeof(float));
  float* ag1  = (float*)alloc((size_t)N * 128 * sizeof(float));
  int* pairs  = (int*)alloc((size_t)G * SCAP * sizeof(int));
  int* offs   = (int*)alloc((size_t)(2 * N) * sizeof(int));
  int* counts = (int*)alloc((size_t)(2 * N) * sizeof(int));
  int* gcur   = (int*)alloc((size_t)(G + 8) * sizeof(int));
  float* pbuf = (float*)alloc(2 * 64 * 64 * sizeof(float));
  (void)ws_size; (void)n_in; (void)out_size;

  // ---- CSR build ----
  hipMemsetAsync(gcur, 0, (size_t)(G + 8) * sizeof(int), stream);
  {
    dim3 gb((E + 4095) / 4096, 2);
    bin_kernel<<<gb, 1024, 0, stream>>>(e1, e1 + E, e2, e2 + E, gcur, pairs, E, G1);
    dim3 gr(G1, 2);
    refine_kernel<<<gr, 1024, 0, stream>>>(gcur, pairs, offs, counts, N, G1);
  }

  // layer 1
  {
    dim3 gg((N + 63) / 64, 2);
    gemm2_kernel<128><<<gg, 256, 0, stream>>>(x1, x2, W1a, W2a, b1a, b2a, h0, h1, N);
  }
  {
    dim3 ga((N + 3) / 4, 4);
    agg128_kernel<<<ga, 256, 0, stream>>>(h0, h1, offs, counts, pairs,
                                          g1a, be1a, g2a, be2a, ag0, ag1, N);
  }
  // layer 2
  {
    dim3 gg((N + 63) / 64, 2);
    gemm2_kernel<64><<<gg, 256, 0, stream>>>(ag0, ag1, W1b, W2b, b1b, b2b, h0, h1, N);
  }
  {
    dim3 ga((N + 3) / 4, 2);
    agg64_kernel<<<ga, 256, 0, stream>>>(h0, h1, offs, counts, pairs,
                                         g1b, be1b, g2b, be2b, ag0, ag1, N);
  }
  // pool + head
  {
    dim3 gp(64, 2);
    pool2_kernel<<<gp, 1024, 0, stream>>>(ag0, ag1, seg1, seg2, pbuf, N);
  }
  head_kernel<<<1, 512, 0, stream>>>(pbuf, Wd, bd, Wo, bo, out);
}